// Round 1
// baseline (102.842 us; speedup 1.0000x reference)
//
#include <hip/hip_runtime.h>

// GFNet-style global filter: out = irfft2( rfft2(x) * W ), ortho norm, 14x14 spatial.
// x: (B=256, N=196, C=768) f32 ; W: (14, 8, C, 2) f32 ; out: (B, 196, C) f32.
//
// Implemented as dense small-DFT stages with compile-time twiddles, vectorized
// over channels (lane dim = channel for coalescing / conflict-free LDS).

static constexpr int CB     = 64;          // channels per block
static constexpr int NT     = 512;         // threads per block (8 waves)
static constexpr int CTILES = 768 / CB;    // 12

// cos/sin(2*pi*k/14), k = 0..13
static constexpr float C14[14] = {
     1.0f,
     0.90096886790241915f,  0.62348980185873359f,  0.22252093395631445f,
    -0.22252093395631434f, -0.62348980185873348f, -0.90096886790241915f,
    -1.0f,
    -0.90096886790241926f, -0.62348980185873371f, -0.22252093395631456f,
     0.22252093395631423f,  0.62348980185873337f,  0.90096886790241904f
};
static constexpr float S14[14] = {
     0.0f,
     0.43388373911755812f,  0.78183148246802980f,  0.97492791218182362f,
     0.97492791218182362f,  0.78183148246802991f,  0.43388373911755823f,
     0.0f,
    -0.43388373911755806f, -0.78183148246802958f, -0.97492791218182362f,
    -0.97492791218182373f, -0.78183148246802991f, -0.43388373911755834f
};

__global__ __launch_bounds__(NT) void gfnet_filter(
    const float* __restrict__ x,
    const float* __restrict__ wgt,
    float* __restrict__ out)
{
    // Union LDS buffer: xs[196][64] f32 (50176 B)  /  G,P [14][8][64] float2 (57344 B)
    __shared__ __align__(16) float U[14336];
    float2* U2 = reinterpret_cast<float2*>(U);

    const int bid = blockIdx.x;
    const int b   = bid / CTILES;
    const int ct  = bid - b * CTILES;
    const int c0  = ct * CB;
    const int tid = threadIdx.x;
    const int wv  = tid >> 6;   // wave id: row-pair index (phases A/D) or u_w (phases B/C)
    const int ln  = tid & 63;   // channel within tile

    // ---------------- stage 0: global -> LDS  xs[s][c] ----------------
    {
        const float* xb = x + (size_t)b * 196 * 768 + c0;
        float4* U4 = reinterpret_cast<float4*>(U);
        #pragma unroll
        for (int it = 0; it < 7; ++it) {
            int idx = tid + it * NT;
            if (idx < 196 * (CB / 4)) {
                int s = idx >> 4, c4 = idx & 15;
                U4[s * 16 + c4] =
                    *reinterpret_cast<const float4*>(xb + (size_t)s * 768 + c4 * 4);
            }
        }
    }
    __syncthreads();

    // ---------------- phase A: rfft along w for rows h0 (and h1) ----------------
    // G[h][u] = sum_w x[h][w] * e^{-2pi i u w / 14},  u = 0..7
    const int h0 = wv, h1 = wv + 8;
    const bool two = (h1 < 14);
    float g0r[8], g0i[8], g1r[8], g1i[8];
    {
        float xr[14];
        #pragma unroll
        for (int w = 0; w < 14; ++w) xr[w] = U[(h0 * 14 + w) * 64 + ln];
        #pragma unroll
        for (int u = 0; u < 8; ++u) {
            float sr = 0.f, si = 0.f;
            #pragma unroll
            for (int w = 0; w < 14; ++w) {
                sr = fmaf(xr[w],  C14[(u * w) % 14], sr);
                si = fmaf(xr[w], -S14[(u * w) % 14], si);
            }
            g0r[u] = sr; g0i[u] = si;
        }
        if (two) {
            float yr[14];
            #pragma unroll
            for (int w = 0; w < 14; ++w) yr[w] = U[(h1 * 14 + w) * 64 + ln];
            #pragma unroll
            for (int u = 0; u < 8; ++u) {
                float sr = 0.f, si = 0.f;
                #pragma unroll
                for (int w = 0; w < 14; ++w) {
                    sr = fmaf(yr[w],  C14[(u * w) % 14], sr);
                    si = fmaf(yr[w], -S14[(u * w) % 14], si);
                }
                g1r[u] = sr; g1i[u] = si;
            }
        } else {
            #pragma unroll
            for (int u = 0; u < 8; ++u) { g1r[u] = 0.f; g1i[u] = 0.f; }
        }
    }

    // preload weights for phase B (this wave handles u_w = wv):
    // wgt flat: ((k*8 + u_w)*768 + c) * 2  -> float2
    float wr[14], wi[14];
    {
        const float2* w2 = reinterpret_cast<const float2*>(wgt);
        #pragma unroll
        for (int k = 0; k < 14; ++k) {
            float2 t = w2[((size_t)k * 8 + wv) * 768 + c0 + ln];
            wr[k] = t.x; wi[k] = t.y;
        }
    }

    __syncthreads();   // all xs reads complete; safe to overwrite union with G

    #pragma unroll
    for (int u = 0; u < 8; ++u)
        U2[(h0 * 8 + u) * 64 + ln] = make_float2(g0r[u], g0i[u]);
    if (two) {
        #pragma unroll
        for (int u = 0; u < 8; ++u)
            U2[(h1 * 8 + u) * 64 + ln] = make_float2(g1r[u], g1i[u]);
    }
    __syncthreads();   // G visible

    // ---------------- phase B read: G[h][u_w=wv] for all h ----------------
    float gr[14], gi[14];
    #pragma unroll
    for (int h = 0; h < 14; ++h) {
        float2 t = U2[(h * 8 + wv) * 64 + ln];
        gr[h] = t.x; gi[h] = t.y;
    }
    __syncthreads();   // all G reads complete; union free for P

    // ---------------- phases B+C: FFT over h, weight, inverse FFT over h ----------------
    // a[k]   = sum_h g[h] e^{-2pi i k h/14}
    // Hm[k]  = a[k] * w[k]
    // P[h']  = sum_k Hm[k] e^{+2pi i k h'/14}
    float Pr[14], Pi[14];
    #pragma unroll
    for (int hp = 0; hp < 14; ++hp) { Pr[hp] = 0.f; Pi[hp] = 0.f; }
    #pragma unroll
    for (int k = 0; k < 14; ++k) {
        float ar = 0.f, ai = 0.f;
        #pragma unroll
        for (int h = 0; h < 14; ++h) {
            const float cc = C14[(k * h) % 14], ss = S14[(k * h) % 14];
            ar = fmaf(gr[h], cc, ar); ar = fmaf(gi[h],  ss, ar);
            ai = fmaf(gi[h], cc, ai); ai = fmaf(gr[h], -ss, ai);
        }
        const float Hr = ar * wr[k] - ai * wi[k];
        const float Hi = ar * wi[k] + ai * wr[k];
        #pragma unroll
        for (int hp = 0; hp < 14; ++hp) {
            const float cc = C14[(k * hp) % 14], ss = S14[(k * hp) % 14];
            Pr[hp] = fmaf(Hr, cc, Pr[hp]); Pr[hp] = fmaf(Hi, -ss, Pr[hp]);
            Pi[hp] = fmaf(Hr, ss, Pi[hp]); Pi[hp] = fmaf(Hi,  cc, Pi[hp]);
        }
    }
    // write P[h'][u_w=wv]
    #pragma unroll
    for (int hp = 0; hp < 14; ++hp)
        U2[(hp * 8 + wv) * 64 + ln] = make_float2(Pr[hp], Pi[hp]);
    __syncthreads();   // P visible

    // ---------------- phase D: inverse rfft along w, write out ----------------
    // out[h'][w'] = (1/196) [ beta_v * Re( P[h'][v] * e^{+2pi i v w'/14} ) summed over v ]
    // beta_0 = beta_7 = 1, else 2.  sin terms vanish at v=0,7 -> numpy c2r semantics.
    #pragma unroll
    for (int rr = 0; rr < 2; ++rr) {
        const int hp = wv + rr * 8;
        if (hp < 14) {
            float pr[8], pi[8];
            #pragma unroll
            for (int v = 0; v < 8; ++v) {
                const float beta = (v == 0 || v == 7) ? (1.0f / 196.0f) : (2.0f / 196.0f);
                float2 t = U2[(hp * 8 + v) * 64 + ln];
                pr[v] = t.x * beta; pi[v] = t.y * beta;
            }
            float* ob = out + ((size_t)b * 196 + (size_t)hp * 14) * 768 + c0 + ln;
            #pragma unroll
            for (int wp = 0; wp < 14; ++wp) {
                float acc = 0.f;
                #pragma unroll
                for (int v = 0; v < 8; ++v) {
                    acc = fmaf(pr[v],  C14[(v * wp) % 14], acc);
                    acc = fmaf(pi[v], -S14[(v * wp) % 14], acc);
                }
                ob[(size_t)wp * 768] = acc;
            }
        }
    }
}

extern "C" void kernel_launch(void* const* d_in, const int* in_sizes, int n_in,
                              void* d_out, int out_size, void* d_ws, size_t ws_size,
                              hipStream_t stream) {
    const float* x   = (const float*)d_in[0];
    const float* wgt = (const float*)d_in[1];
    float*       o   = (float*)d_out;

    const int B = in_sizes[0] / (196 * 768);   // 256
    dim3 grid(B * CTILES), block(NT);
    gfnet_filter<<<grid, block, 0, stream>>>(x, wgt, o);
}

// Round 2
// 88.747 us; speedup vs baseline: 1.1588x; 1.1588x over previous
//
#include <hip/hip_runtime.h>

// GFNet global filter: out = irfft2( rfft2(x) * W ), ortho norm, 14x14 spatial.
// x: (B=256, N=196, C=768) f32 ; W: (14, 8, C, 2) f32 ; out: (B, 196, C) f32.
//
// Dense small-DFT stages, compile-time twiddles, lane dim = channel.
// h-FFT pair (fwd+inv) uses radix-2 (14 = 2x7) factorization.
// LDS: single 28672 B buffer, transposes done in two half-rounds.

static constexpr int CB     = 64;          // channels per block
static constexpr int NT     = 512;         // threads per block (8 waves)
static constexpr int CTILES = 768 / CB;    // 12

// cos/sin(2*pi*k/14), k = 0..13
static constexpr float C14[14] = {
     1.0f,
     0.90096886790241915f,  0.62348980185873359f,  0.22252093395631445f,
    -0.22252093395631434f, -0.62348980185873348f, -0.90096886790241915f,
    -1.0f,
    -0.90096886790241926f, -0.62348980185873371f, -0.22252093395631456f,
     0.22252093395631423f,  0.62348980185873337f,  0.90096886790241904f
};
static constexpr float S14[14] = {
     0.0f,
     0.43388373911755812f,  0.78183148246802980f,  0.97492791218182362f,
     0.97492791218182362f,  0.78183148246802991f,  0.43388373911755823f,
     0.0f,
    -0.43388373911755806f, -0.78183148246802958f, -0.97492791218182362f,
    -0.97492791218182373f, -0.78183148246802991f, -0.43388373911755834f
};

__global__ __launch_bounds__(NT) void gfnet_filter(
    const float* __restrict__ x,
    const float* __restrict__ wgt,
    float* __restrict__ out)
{
    // 28672 B union buffer:
    //   G rounds: [h=0..13][j=0..3][64] float2   (j = u or u-4)
    //   P rounds: [m=0..6][v=0..7][64] float2
    __shared__ __align__(16) float2 T[14 * 4 * 64];

    const int bid = blockIdx.x;
    const int b   = bid / CTILES;
    const int ct  = bid - b * CTILES;
    const int c0  = ct * CB;
    const int tid = threadIdx.x;
    const int wv  = tid >> 6;   // wave id
    const int ln  = tid & 63;   // channel within tile

    // ---------------- phase A: rfft along w, rows h0 (and h1), direct global ----------------
    const int h0 = wv, h1 = wv + 8;
    const bool two = (wv < 6);
    const float* xb = x + (size_t)b * 196 * 768 + c0 + ln;

    float g0r[8], g0i[8], g1r[8], g1i[8];
    {
        float xr0[14], xr1[14];
        #pragma unroll
        for (int w = 0; w < 14; ++w) xr0[w] = xb[(size_t)(h0 * 14 + w) * 768];
        if (two) {
            #pragma unroll
            for (int w = 0; w < 14; ++w) xr1[w] = xb[(size_t)(h1 * 14 + w) * 768];
        }
        #pragma unroll
        for (int u = 0; u < 8; ++u) {
            float sr = 0.f, si = 0.f;
            #pragma unroll
            for (int w = 0; w < 14; ++w) {
                sr = fmaf(xr0[w],  C14[(u * w) % 14], sr);
                si = fmaf(xr0[w], -S14[(u * w) % 14], si);
            }
            g0r[u] = sr; g0i[u] = si;
        }
        if (two) {
            #pragma unroll
            for (int u = 0; u < 8; ++u) {
                float sr = 0.f, si = 0.f;
                #pragma unroll
                for (int w = 0; w < 14; ++w) {
                    sr = fmaf(xr1[w],  C14[(u * w) % 14], sr);
                    si = fmaf(xr1[w], -S14[(u * w) % 14], si);
                }
                g1r[u] = sr; g1i[u] = si;
            }
        }
    }

    // ---------------- G transpose, two half-rounds (u=0..3 then u=4..7) ----------------
    float gr[14], gi[14];

    #pragma unroll
    for (int u = 0; u < 4; ++u)
        T[(h0 * 4 + u) * 64 + ln] = make_float2(g0r[u], g0i[u]);
    if (two) {
        #pragma unroll
        for (int u = 0; u < 4; ++u)
            T[(h1 * 4 + u) * 64 + ln] = make_float2(g1r[u], g1i[u]);
    }
    __syncthreads();
    if (wv < 4) {
        #pragma unroll
        for (int h = 0; h < 14; ++h) {
            float2 t = T[(h * 4 + wv) * 64 + ln];
            gr[h] = t.x; gi[h] = t.y;
        }
    }
    __syncthreads();
    #pragma unroll
    for (int u = 0; u < 4; ++u)
        T[(h0 * 4 + u) * 64 + ln] = make_float2(g0r[u + 4], g0i[u + 4]);
    if (two) {
        #pragma unroll
        for (int u = 0; u < 4; ++u)
            T[(h1 * 4 + u) * 64 + ln] = make_float2(g1r[u + 4], g1i[u + 4]);
    }
    __syncthreads();
    if (wv >= 4) {
        #pragma unroll
        for (int h = 0; h < 14; ++h) {
            float2 t = T[(h * 4 + (wv - 4)) * 64 + ln];
            gr[h] = t.x; gi[h] = t.y;
        }
    }
    __syncthreads();

    // ---------------- phase B (radix-2): E[k] over even h, O'[k] over odd h ----------------
    // a[k] = E[k] + O'[k], a[k+7] = E[k] - O'[k], k = 0..6
    float Er[7], Ei[7], Or_[7], Oi_[7];
    #pragma unroll
    for (int k = 0; k < 7; ++k) { Er[k] = Ei[k] = Or_[k] = Oi_[k] = 0.f; }
    #pragma unroll
    for (int h = 0; h < 14; ++h) {
        const float a = gr[h], bb = gi[h];
        if ((h & 1) == 0) {
            #pragma unroll
            for (int k = 0; k < 7; ++k) {
                const float c = C14[(k * h) % 14], s = S14[(k * h) % 14];
                Er[k] = fmaf(a,  c, Er[k]); Er[k] = fmaf(bb,  s, Er[k]);
                Ei[k] = fmaf(bb, c, Ei[k]); Ei[k] = fmaf(a,  -s, Ei[k]);
            }
        } else {
            #pragma unroll
            for (int k = 0; k < 7; ++k) {
                const float c = C14[(k * h) % 14], s = S14[(k * h) % 14];
                Or_[k] = fmaf(a,  c, Or_[k]); Or_[k] = fmaf(bb,  s, Or_[k]);
                Oi_[k] = fmaf(bb, c, Oi_[k]); Oi_[k] = fmaf(a,  -s, Oi_[k]);
            }
        }
    }

    // ---------------- weight + phase C (radix-2 scatter): Q over even k, R over odd k ----------------
    // P[m] = Q[m] + R[m], P[m+7] = Q[m] - R[m], m = 0..6
    float Qr[7], Qi[7], Rr[7], Ri[7];
    #pragma unroll
    for (int m = 0; m < 7; ++m) { Qr[m] = Qi[m] = Rr[m] = Ri[m] = 0.f; }
    {
        const float2* w2 = reinterpret_cast<const float2*>(wgt);
        const float2* wb = w2 + (size_t)wv * 768 + c0 + ln;
        #pragma unroll
        for (int k = 0; k < 14; ++k) {
            const int kk = k % 7;
            const float ar = (k < 7) ? (Er[kk] + Or_[kk]) : (Er[kk] - Or_[kk]);
            const float ai = (k < 7) ? (Ei[kk] + Oi_[kk]) : (Ei[kk] - Oi_[kk]);
            const float2 wt = wb[(size_t)k * 8 * 768];
            const float Hr = fmaf(ar, wt.x, -ai * wt.y);
            const float Hi = fmaf(ar, wt.y,  ai * wt.x);
            if ((k & 1) == 0) {
                #pragma unroll
                for (int m = 0; m < 7; ++m) {
                    const float c = C14[(k * m) % 14], s = S14[(k * m) % 14];
                    Qr[m] = fmaf(Hr, c, Qr[m]); Qr[m] = fmaf(Hi, -s, Qr[m]);
                    Qi[m] = fmaf(Hr, s, Qi[m]); Qi[m] = fmaf(Hi,  c, Qi[m]);
                }
            } else {
                #pragma unroll
                for (int m = 0; m < 7; ++m) {
                    const float c = C14[(k * m) % 14], s = S14[(k * m) % 14];
                    Rr[m] = fmaf(Hr, c, Rr[m]); Rr[m] = fmaf(Hi, -s, Rr[m]);
                    Ri[m] = fmaf(Hr, s, Ri[m]); Ri[m] = fmaf(Hi,  c, Ri[m]);
                }
            }
        }
    }

    // ---------------- P transpose + phase D, row-split rounds ----------------
    float* ob = out + (size_t)b * 196 * 768 + c0 + ln;

    // round 1: rows 0..6, P[m] = Q + R
    #pragma unroll
    for (int m = 0; m < 7; ++m)
        T[(m * 8 + wv) * 64 + ln] = make_float2(Qr[m] + Rr[m], Qi[m] + Ri[m]);
    __syncthreads();
    if (wv < 7) {
        float pr[8], pi[8];
        #pragma unroll
        for (int v = 0; v < 8; ++v) {
            const float beta = (v == 0 || v == 7) ? (1.0f / 196.0f) : (2.0f / 196.0f);
            float2 t = T[(wv * 8 + v) * 64 + ln];
            pr[v] = t.x * beta; pi[v] = t.y * beta;
        }
        #pragma unroll
        for (int wp = 0; wp < 14; ++wp) {
            float acc = 0.f;
            #pragma unroll
            for (int v = 0; v < 8; ++v) {
                acc = fmaf(pr[v],  C14[(v * wp) % 14], acc);
                acc = fmaf(pi[v], -S14[(v * wp) % 14], acc);
            }
            ob[(size_t)(wv * 14 + wp) * 768] = acc;
        }
    }
    __syncthreads();
    // round 2: rows 7..13, P[m+7] = Q - R
    #pragma unroll
    for (int m = 0; m < 7; ++m)
        T[(m * 8 + wv) * 64 + ln] = make_float2(Qr[m] - Rr[m], Qi[m] - Ri[m]);
    __syncthreads();
    if (wv < 7) {
        float pr[8], pi[8];
        #pragma unroll
        for (int v = 0; v < 8; ++v) {
            const float beta = (v == 0 || v == 7) ? (1.0f / 196.0f) : (2.0f / 196.0f);
            float2 t = T[(wv * 8 + v) * 64 + ln];
            pr[v] = t.x * beta; pi[v] = t.y * beta;
        }
        #pragma unroll
        for (int wp = 0; wp < 14; ++wp) {
            float acc = 0.f;
            #pragma unroll
            for (int v = 0; v < 8; ++v) {
                acc = fmaf(pr[v],  C14[(v * wp) % 14], acc);
                acc = fmaf(pi[v], -S14[(v * wp) % 14], acc);
            }
            ob[(size_t)((wv + 7) * 14 + wp) * 768] = acc;
        }
    }
}

extern "C" void kernel_launch(void* const* d_in, const int* in_sizes, int n_in,
                              void* d_out, int out_size, void* d_ws, size_t ws_size,
                              hipStream_t stream) {
    const float* x   = (const float*)d_in[0];
    const float* wgt = (const float*)d_in[1];
    float*       o   = (float*)d_out;

    const int B = in_sizes[0] / (196 * 768);   // 256
    dim3 grid(B * CTILES), block(NT);
    gfnet_filter<<<grid, block, 0, stream>>>(x, wgt, o);
}

// Round 3
// 70.932 us; speedup vs baseline: 1.4499x; 1.2512x over previous
//
#include <hip/hip_runtime.h>

// GFNet global filter: out = irfft2( rfft2(x) * W ), ortho norm, 14x14 spatial.
// x: (B=256, N=196, C=768) f32 ; W: (14, 8, C, 2) f32 ; out: (B, 196, C) f32.
//
// Dense small-DFT stages with compile-time twiddles, lane dim = channel.
// All stages use cos/sin symmetry pairing (j <-> 14-j); the h-FFT pair also
// uses radix-2 (14 = 2x7). G transpose stored compact (u=0,7 are pure real):
// 50176 B LDS, 3 blocks/CU. P transposed as re/im rounds reusing the buffer.

static constexpr int CB     = 64;
static constexpr int NT     = 512;
static constexpr int CTILES = 768 / CB;   // 12

// cos/sin(2*pi*k/14)
static constexpr float C14[14] = {
     1.0f,
     0.90096886790241915f,  0.62348980185873359f,  0.22252093395631445f,
    -0.22252093395631434f, -0.62348980185873348f, -0.90096886790241915f,
    -1.0f,
    -0.90096886790241926f, -0.62348980185873371f, -0.22252093395631456f,
     0.22252093395631423f,  0.62348980185873337f,  0.90096886790241904f
};
static constexpr float S14[14] = {
     0.0f,
     0.43388373911755812f,  0.78183148246802980f,  0.97492791218182362f,
     0.97492791218182362f,  0.78183148246802991f,  0.43388373911755823f,
     0.0f,
    -0.43388373911755806f, -0.78183148246802958f, -0.97492791218182362f,
    -0.97492791218182373f, -0.78183148246802991f, -0.43388373911755834f
};

__global__ __launch_bounds__(NT, 6) void gfnet_filter(
    const float* __restrict__ x,
    const float* __restrict__ wgt,
    float* __restrict__ out)
{
    // 50176 B union buffer:
    //   G rounds: per h (stride 896 floats): [0:64)=u0.re, [64+ (j-1)*128): float2 u=j (j=1..6), [832:896)=u7.re
    //   P rounds: [m=0..13][v=0..7][64] floats (28672 B)
    __shared__ __align__(16) float LB[12544];

    const int bid = blockIdx.x;
    const int b   = bid / CTILES;
    const int ct  = bid - b * CTILES;
    const int c0  = ct * CB;
    const int tid = threadIdx.x;
    const int wv  = tid >> 6;
    const int ln  = tid & 63;
    const bool two = (wv < 6);
    const int r0 = wv;         // rows r0 (and r1) for phases A and D
    const int r1 = wv + 8;

    const float* xb = x + (size_t)b * 196 * 768 + c0 + ln;

    // ---------------- phase A: rfft along w (symmetry-paired) ----------------
    float A0r[8], A0i[7], A1r[8], A1i[7];   // i-index 1..6 used
    {
        float v0[14], v1[14];
        #pragma unroll
        for (int w = 0; w < 14; ++w) v0[w] = xb[(size_t)(r0 * 14 + w) * 768];
        if (two) {
            #pragma unroll
            for (int w = 0; w < 14; ++w) v1[w] = xb[(size_t)(r1 * 14 + w) * 768];
        }
        {
            float s[7], d[7];
            #pragma unroll
            for (int j = 1; j <= 6; ++j) { s[j] = v0[j] + v0[14 - j]; d[j] = v0[j] - v0[14 - j]; }
            A0r[0] = v0[0] + v0[7] + s[1] + s[2] + s[3] + s[4] + s[5] + s[6];
            A0r[7] = v0[0] - v0[7] - s[1] + s[2] - s[3] + s[4] - s[5] + s[6];
            #pragma unroll
            for (int u = 1; u <= 6; ++u) {
                float re = (u & 1) ? (v0[0] - v0[7]) : (v0[0] + v0[7]);
                float im = 0.f;
                #pragma unroll
                for (int j = 1; j <= 6; ++j) {
                    re = fmaf(s[j],  C14[(u * j) % 14], re);
                    im = fmaf(d[j], -S14[(u * j) % 14], im);
                }
                A0r[u] = re; A0i[u] = im;
            }
        }
        if (two) {
            float s[7], d[7];
            #pragma unroll
            for (int j = 1; j <= 6; ++j) { s[j] = v1[j] + v1[14 - j]; d[j] = v1[j] - v1[14 - j]; }
            A1r[0] = v1[0] + v1[7] + s[1] + s[2] + s[3] + s[4] + s[5] + s[6];
            A1r[7] = v1[0] - v1[7] - s[1] + s[2] - s[3] + s[4] - s[5] + s[6];
            #pragma unroll
            for (int u = 1; u <= 6; ++u) {
                float re = (u & 1) ? (v1[0] - v1[7]) : (v1[0] + v1[7]);
                float im = 0.f;
                #pragma unroll
                for (int j = 1; j <= 6; ++j) {
                    re = fmaf(s[j],  C14[(u * j) % 14], re);
                    im = fmaf(d[j], -S14[(u * j) % 14], im);
                }
                A1r[u] = re; A1i[u] = im;
            }
        }
    }

    // ---------------- G transpose (compact, single round) ----------------
    {
        float* g0 = LB + r0 * 896;
        g0[ln]       = A0r[0];
        g0[832 + ln] = A0r[7];
        #pragma unroll
        for (int j = 1; j <= 6; ++j)
            reinterpret_cast<float2*>(g0 + 64 + (j - 1) * 128)[ln] = make_float2(A0r[j], A0i[j]);
        if (two) {
            float* g1 = LB + r1 * 896;
            g1[ln]       = A1r[0];
            g1[832 + ln] = A1r[7];
            #pragma unroll
            for (int j = 1; j <= 6; ++j)
                reinterpret_cast<float2*>(g1 + 64 + (j - 1) * 128)[ln] = make_float2(A1r[j], A1i[j]);
        }
    }
    __syncthreads();                    // bar1: G visible
    float gr[14], gi[14];
    if (wv == 0) {
        #pragma unroll
        for (int h = 0; h < 14; ++h) { gr[h] = LB[h * 896 + ln]; gi[h] = 0.f; }
    } else if (wv == 7) {
        #pragma unroll
        for (int h = 0; h < 14; ++h) { gr[h] = LB[h * 896 + 832 + ln]; gi[h] = 0.f; }
    } else {
        #pragma unroll
        for (int h = 0; h < 14; ++h) {
            float2 t = reinterpret_cast<float2*>(LB + h * 896 + 64 + (wv - 1) * 128)[ln];
            gr[h] = t.x; gi[h] = t.y;
        }
    }
    __syncthreads();                    // bar2: G reads done, buffer reusable

    // ---------------- phase B: a[k] = FFT_h(g), radix-2 + pairing ----------------
    float esr[3], esi[3], edr[3], edi[3], osr[3], osi[3], odr[3], odi[3];
    #pragma unroll
    for (int i = 0; i < 3; ++i) {
        int j = 2 * (i + 1);
        esr[i] = gr[j] + gr[14 - j]; esi[i] = gi[j] + gi[14 - j];
        edr[i] = gr[j] - gr[14 - j]; edi[i] = gi[j] - gi[14 - j];
        j = 2 * i + 1;
        osr[i] = gr[j] + gr[14 - j]; osi[i] = gi[j] + gi[14 - j];
        odr[i] = gr[j] - gr[14 - j]; odi[i] = gi[j] - gi[14 - j];
    }
    float Ekr[7], Eki[7], Okr[7], Oki[7];
    Ekr[0] = gr[0] + esr[0] + esr[1] + esr[2];
    Eki[0] = gi[0] + esi[0] + esi[1] + esi[2];
    Okr[0] = gr[7] + osr[0] + osr[1] + osr[2];
    Oki[0] = gi[7] + osi[0] + osi[1] + osi[2];
    #pragma unroll
    for (int k = 1; k <= 6; ++k) {
        float er = gr[0], ei = gi[0];
        #pragma unroll
        for (int i = 0; i < 3; ++i) {
            const int j = 2 * (i + 1);
            const float c = C14[(j * k) % 14], s2 = S14[(j * k) % 14];
            er = fmaf(esr[i], c, er); er = fmaf(edi[i],  s2, er);
            ei = fmaf(esi[i], c, ei); ei = fmaf(edr[i], -s2, ei);
        }
        Ekr[k] = er; Eki[k] = ei;
        float onr = (k & 1) ? -gr[7] : gr[7];
        float oni = (k & 1) ? -gi[7] : gi[7];
        #pragma unroll
        for (int i = 0; i < 3; ++i) {
            const int j = 2 * i + 1;
            const float c = C14[(j * k) % 14], s2 = S14[(j * k) % 14];
            onr = fmaf(osr[i], c, onr); onr = fmaf(odi[i],  s2, onr);
            oni = fmaf(osi[i], c, oni); oni = fmaf(odr[i], -s2, oni);
        }
        Okr[k] = onr; Oki[k] = oni;
    }

    // ---------------- weight multiply: H[k] = a[k] * w[k] ----------------
    float Hr[14], Hi[14];
    {
        const float2* wb = reinterpret_cast<const float2*>(wgt) + (size_t)wv * 768 + c0 + ln;
        #pragma unroll
        for (int k = 0; k < 7; ++k) {
            const float2 wA = wb[(size_t)k * (8 * 768)];
            const float2 wB = wb[(size_t)(k + 7) * (8 * 768)];
            const float ar = Ekr[k] + Okr[k], ai = Eki[k] + Oki[k];
            const float br = Ekr[k] - Okr[k], bi = Eki[k] - Oki[k];
            Hr[k]     = fmaf(ar, wA.x, -(ai * wA.y));
            Hi[k]     = fmaf(ar, wA.y,   ai * wA.x);
            Hr[k + 7] = fmaf(br, wB.x, -(bi * wB.y));
            Hi[k + 7] = fmaf(br, wB.y,   bi * wB.x);
        }
    }

    // ---------------- phase C: P = IFFT_h(H), radix-2 + pairing ----------------
    float qsr[3], qsi[3], qdr[3], qdi[3], rsr[3], rsi[3], rdr[3], rdi[3];
    #pragma unroll
    for (int i = 0; i < 3; ++i) {
        int j = 2 * (i + 1);
        qsr[i] = Hr[j] + Hr[14 - j]; qsi[i] = Hi[j] + Hi[14 - j];
        qdr[i] = Hr[j] - Hr[14 - j]; qdi[i] = Hi[j] - Hi[14 - j];
        j = 2 * i + 1;
        rsr[i] = Hr[j] + Hr[14 - j]; rsi[i] = Hi[j] + Hi[14 - j];
        rdr[i] = Hr[j] - Hr[14 - j]; rdi[i] = Hi[j] - Hi[14 - j];
    }
    float Qr[7], Qi[7], Rr[7], Ri[7];
    Qr[0] = Hr[0] + qsr[0] + qsr[1] + qsr[2];
    Qi[0] = Hi[0] + qsi[0] + qsi[1] + qsi[2];
    Rr[0] = Hr[7] + rsr[0] + rsr[1] + rsr[2];
    Ri[0] = Hi[7] + rsi[0] + rsi[1] + rsi[2];
    #pragma unroll
    for (int m = 1; m <= 6; ++m) {
        float qr = Hr[0], qi2 = Hi[0];
        #pragma unroll
        for (int i = 0; i < 3; ++i) {
            const int j = 2 * (i + 1);
            const float c = C14[(j * m) % 14], s2 = S14[(j * m) % 14];
            qr  = fmaf(qsr[i], c, qr);  qr  = fmaf(qdi[i], -s2, qr);
            qi2 = fmaf(qsi[i], c, qi2); qi2 = fmaf(qdr[i],  s2, qi2);
        }
        Qr[m] = qr; Qi[m] = qi2;
        float rr = (m & 1) ? -Hr[7] : Hr[7];
        float ri2 = (m & 1) ? -Hi[7] : Hi[7];
        #pragma unroll
        for (int i = 0; i < 3; ++i) {
            const int j = 2 * i + 1;
            const float c = C14[(j * m) % 14], s2 = S14[(j * m) % 14];
            rr  = fmaf(rsr[i], c, rr);  rr  = fmaf(rdi[i], -s2, rr);
            ri2 = fmaf(rsi[i], c, ri2); ri2 = fmaf(rdr[i],  s2, ri2);
        }
        Rr[m] = rr; Ri[m] = ri2;
    }

    // ---------------- P transpose (re round) + phase D t1 ----------------
    #pragma unroll
    for (int m = 0; m < 7; ++m) {
        LB[(m * 8 + wv) * 64 + ln]       = Qr[m] + Rr[m];
        LB[((m + 7) * 8 + wv) * 64 + ln] = Qr[m] - Rr[m];
    }
    __syncthreads();                    // bar3: Pr visible
    float t1a[8], t1b[8];
    {
        float a0[8], a1[8];
        #pragma unroll
        for (int v = 0; v < 8; ++v) {
            const float beta = (v == 0 || v == 7) ? (1.0f / 196.0f) : (2.0f / 196.0f);
            a0[v] = LB[(r0 * 8 + v) * 64 + ln] * beta;
            if (two) a1[v] = LB[(r1 * 8 + v) * 64 + ln] * beta;
        }
        t1a[0] = a0[0] + a0[7] + a0[1] + a0[2] + a0[3] + a0[4] + a0[5] + a0[6];
        t1a[7] = a0[0] - a0[7] - a0[1] + a0[2] - a0[3] + a0[4] - a0[5] + a0[6];
        #pragma unroll
        for (int wp = 1; wp <= 6; ++wp) {
            float t = (wp & 1) ? (a0[0] - a0[7]) : (a0[0] + a0[7]);
            #pragma unroll
            for (int v = 1; v <= 6; ++v) t = fmaf(a0[v], C14[(v * wp) % 14], t);
            t1a[wp] = t;
        }
        if (two) {
            t1b[0] = a1[0] + a1[7] + a1[1] + a1[2] + a1[3] + a1[4] + a1[5] + a1[6];
            t1b[7] = a1[0] - a1[7] - a1[1] + a1[2] - a1[3] + a1[4] - a1[5] + a1[6];
            #pragma unroll
            for (int wp = 1; wp <= 6; ++wp) {
                float t = (wp & 1) ? (a1[0] - a1[7]) : (a1[0] + a1[7]);
                #pragma unroll
                for (int v = 1; v <= 6; ++v) t = fmaf(a1[v], C14[(v * wp) % 14], t);
                t1b[wp] = t;
            }
        }
    }
    __syncthreads();                    // bar4: Pr reads done

    // ---------------- P transpose (im round) + phase D t2 + stores ----------------
    #pragma unroll
    for (int m = 0; m < 7; ++m) {
        LB[(m * 8 + wv) * 64 + ln]       = Qi[m] + Ri[m];
        LB[((m + 7) * 8 + wv) * 64 + ln] = Qi[m] - Ri[m];
    }
    __syncthreads();                    // bar5: Pi visible
    {
        float* ob = out + (size_t)b * 196 * 768 + c0 + ln;
        float b0[7], b1[7];
        #pragma unroll
        for (int v = 1; v <= 6; ++v) {
            b0[v] = LB[(r0 * 8 + v) * 64 + ln] * (2.0f / 196.0f);
            if (two) b1[v] = LB[(r1 * 8 + v) * 64 + ln] * (2.0f / 196.0f);
        }
        ob[(size_t)(r0 * 14 + 0) * 768] = t1a[0];
        ob[(size_t)(r0 * 14 + 7) * 768] = t1a[7];
        #pragma unroll
        for (int wp = 1; wp <= 6; ++wp) {
            float t = 0.f;
            #pragma unroll
            for (int v = 1; v <= 6; ++v) t = fmaf(b0[v], S14[(v * wp) % 14], t);
            ob[(size_t)(r0 * 14 + wp) * 768]      = t1a[wp] - t;
            ob[(size_t)(r0 * 14 + 14 - wp) * 768] = t1a[wp] + t;
        }
        if (two) {
            ob[(size_t)(r1 * 14 + 0) * 768] = t1b[0];
            ob[(size_t)(r1 * 14 + 7) * 768] = t1b[7];
            #pragma unroll
            for (int wp = 1; wp <= 6; ++wp) {
                float t = 0.f;
                #pragma unroll
                for (int v = 1; v <= 6; ++v) t = fmaf(b1[v], S14[(v * wp) % 14], t);
                ob[(size_t)(r1 * 14 + wp) * 768]      = t1b[wp] - t;
                ob[(size_t)(r1 * 14 + 14 - wp) * 768] = t1b[wp] + t;
            }
        }
    }
}

extern "C" void kernel_launch(void* const* d_in, const int* in_sizes, int n_in,
                              void* d_out, int out_size, void* d_ws, size_t ws_size,
                              hipStream_t stream) {
    const float* x   = (const float*)d_in[0];
    const float* wgt = (const float*)d_in[1];
    float*       o   = (float*)d_out;

    const int B = in_sizes[0] / (196 * 768);   // 256
    dim3 grid(B * CTILES), block(NT);
    gfnet_filter<<<grid, block, 0, stream>>>(x, wgt, o);
}